// Round 13
// baseline (191.491 us; speedup 1.0000x reference)
//
#include <hip/hip_runtime.h>
#include <hip/hip_bf16.h>

typedef __hip_bfloat16 bf16;
typedef __attribute__((ext_vector_type(8))) short bf16x8;
typedef __attribute__((ext_vector_type(4))) float f32x4;
typedef __attribute__((ext_vector_type(2))) float f32x2;
typedef unsigned int uint32;
typedef long long i64;

#define NB 8
#define NC 256
#define NH 128
#define NW 128
#define NHW 16384
#define QSTR 40    // k_qk Xl stride: 80B = 5*16B aligned

static __device__ __forceinline__ float b2f(bf16 v){ return __bfloat162float(v); }
static __device__ __forceinline__ bf16  f2b(float v){ return __float2bfloat16(v); }
// fp8 LDS tile swizzle (byte space, 8B granule)
static __device__ __forceinline__ int swz8(int row, int col){ return row*128 + (col ^ ((row&15)<<3)); }

// fp8 e4m3 (OCP) helpers
static __device__ __forceinline__ uint32 pk_fp8x4(float a, float b, float c, float d){
    int v = __builtin_amdgcn_cvt_pk_fp8_f32(a, b, 0, false);
    v = __builtin_amdgcn_cvt_pk_fp8_f32(c, d, v, true);
    return (uint32)v;
}
static __device__ __forceinline__ i64 u2ll(uint2 u){
    union { uint2 a; i64 b; } c; c.a = u; return c.b;
}
static __device__ __forceinline__ i64 bf8_to_fp8(bf16x8 v){
    union { bf16x8 v8; bf16 h[8]; } a; a.v8 = v;
    uint2 r;
    r.x = pk_fp8x4(b2f(a.h[0]), b2f(a.h[1]), b2f(a.h[2]), b2f(a.h[3]));
    r.y = pk_fp8x4(b2f(a.h[4]), b2f(a.h[5]), b2f(a.h[6]), b2f(a.h[7]));
    return u2ll(r);
}

// ---------------- prep: wvb8[co][c] fp8, wqkb[o][c] bf16 (o<32: Wq row, o>=32: Wk row) --------
__global__ __launch_bounds__(256) void k_prep(const float* __restrict__ Wq,
                                              const float* __restrict__ Wk,
                                              const float* __restrict__ Wv,
                                              unsigned char* __restrict__ wvb8,
                                              bf16* __restrict__ wqkb){
    int idx = blockIdx.x*256 + threadIdx.x;
    if (idx < 32768){
        int v = __builtin_amdgcn_cvt_pk_fp8_f32(Wv[2*idx], Wv[2*idx+1], 0, false);
        *(unsigned short*)(wvb8 + 2*idx) = (unsigned short)(v & 0xffff);
    } else if (idx < 49152){
        int i2 = idx - 32768;                     // 0..16383 -> [64][256] flat
        wqkb[i2] = f2b(i2 < 8192 ? Wq[i2] : Wk[i2 - 8192]);
    }
}

// ---------------- 64x64 tiled transpose: x fp32 -> xbf bf16 [c][h][w] + xcm8 fp8 [c][w][h] ----
__global__ __launch_bounds__(256) void k_tr(const float* __restrict__ x,
                                            unsigned char* __restrict__ xcm8,
                                            bf16* __restrict__ xbf){
    __shared__ float tile[64][65];
    int img = blockIdx.y;                 // 0..2047 (b*c)
    int tw = blockIdx.x & 1, th = blockIdx.x >> 1;
    int h0 = th*64, w0 = tw*64;
    int t = threadIdx.x;
    const float* src = x + (size_t)img*NHW;
    #pragma unroll
    for (int it=0; it<4; it++){
        int fl = it*256 + t;
        int row = fl >> 4, c4 = (fl & 15) * 4;
        float4 v = *(const float4*)(src + (size_t)(h0+row)*NW + w0 + c4);
        tile[row][c4+0]=v.x; tile[row][c4+1]=v.y; tile[row][c4+2]=v.z; tile[row][c4+3]=v.w;
    }
    __syncthreads();
    bf16* db = xbf + (size_t)img*NHW;
    #pragma unroll
    for (int it=0; it<4; it++){
        int fl = it*256 + t;
        int row = fl >> 4, c4 = (fl & 15) * 4;
        union { ushort4 u; bf16 h[4]; } pk;
        #pragma unroll
        for (int k2=0;k2<4;k2++) pk.h[k2] = f2b(tile[row][c4+k2]);
        *(ushort4*)(db + (size_t)(h0+row)*NW + w0 + c4) = pk.u;
    }
    unsigned char* dc = xcm8 + (size_t)img*NHW;
    #pragma unroll
    for (int it=0; it<4; it++){
        int fl = it*256 + t;
        int wl = fl >> 4, hq = (fl & 15) * 4;
        uint32 u = pk_fp8x4(tile[hq+0][wl], tile[hq+1][wl], tile[hq+2][wl], tile[hq+3][wl]);
        *(uint32*)(dc + (size_t)(w0+wl)*NH + h0 + hq) = u;
    }
}

// ---------------- qk conv (MFMA): qk8[b][p][64] = {q fp8 0..31 | k fp8 32..63} ----------------
__global__ __launch_bounds__(512) void k_qk(const bf16* __restrict__ xbf,
                                            const bf16* __restrict__ wqkb,
                                            const float* __restrict__ bq,
                                            const float* __restrict__ bk,
                                            unsigned char* __restrict__ qk8){
    __shared__ __align__(16) bf16 Xl[256*QSTR];
    int t = threadIdx.x;
    int wv = t >> 6, l = t & 63, lr = l & 15, lg = l >> 4;
    int b = blockIdx.y;
    int p0 = blockIdx.x * 256;
    int q4 = t & 3, pb = ((t >> 2) & 63) * 4, chi = t >> 8;   // chi 0/1
    f32x4 acc[4][2] = {};
    for (int kb = 0; kb < 8; kb++){
        if (kb) __syncthreads();
        #pragma unroll
        for (int it = 0; it < 4; it++){
            int cl = it*8 + chi*4;                // chunk-local c base (lane adds q4)
            const bf16* xp = xbf + ((size_t)(b*NC + kb*32 + cl + q4))*NHW + p0 + pb;
            union { ushort4 u; bf16 h[4]; } ld;
            ld.u = *(const ushort4*)xp;
            float e[4] = {b2f(ld.h[0]), b2f(ld.h[1]), b2f(ld.h[2]), b2f(ld.h[3])};
            float s1[4], s2[4];
            #pragma unroll
            for (int j=0;j<4;j++){
                float ex = __shfl_xor(e[j^1], 1);
                s1[j] = ((j&1)==(q4&1)) ? e[j] : ex;
            }
            #pragma unroll
            for (int j=0;j<4;j++){
                float ex = __shfl_xor(s1[j^2], 2);
                s2[j] = ((j&2)==(q4&2)) ? s1[j] : ex;
            }
            union { ushort4 u; bf16 h[4]; } pk;
            #pragma unroll
            for (int j=0;j<4;j++) pk.h[j] = f2b(s2[j]);
            *(ushort4*)(Xl + (pb + q4)*QSTR + cl) = pk.u;
        }
        __syncthreads();
        bf16x8 bf_[2];
        #pragma unroll
        for (int nt=0;nt<2;nt++)
            bf_[nt] = *(const bf16x8*)(Xl + (wv*32 + nt*16 + lr)*QSTR + lg*8);
        #pragma unroll
        for (int mt=0;mt<4;mt++){
            bf16x8 af = *(const bf16x8*)(wqkb + (size_t)(mt*16 + lr)*NC + kb*32 + lg*8);
            acc[mt][0] = __builtin_amdgcn_mfma_f32_16x16x32_bf16(af, bf_[0], acc[mt][0], 0,0,0);
            acc[mt][1] = __builtin_amdgcn_mfma_f32_16x16x32_bf16(af, bf_[1], acc[mt][1], 0,0,0);
        }
    }
    #pragma unroll
    for (int mt=0;mt<4;mt++){
        int o0 = mt*16 + lg*4;                        // 0..63 (q rows 0..31, k rows 32..63)
        float4 bb = (mt < 2) ? *(const float4*)(bq + o0)
                             : *(const float4*)(bk + o0 - 32);
        #pragma unroll
        for (int nt=0;nt<2;nt++){
            int p = p0 + wv*32 + nt*16 + lr;
            uint32 v = pk_fp8x4(acc[mt][nt][0] + bb.x, acc[mt][nt][1] + bb.y,
                                acc[mt][nt][2] + bb.z, acc[mt][nt][3] + bb.w);
            *(uint32*)(qk8 + ((size_t)b*NHW + p)*64 + o0) = v;
        }
    }
}

// ---------------- column attention (fp8 MFMA): unnormalized aggH (fp8) + lH ----------------
__global__ __launch_bounds__(512, 6) void k_colagg(const unsigned char* __restrict__ qk8,
                                                   const unsigned char* __restrict__ xcm8,
                                                   unsigned char* __restrict__ agg8,
                                                   float* __restrict__ lH){
    __shared__ __align__(16) unsigned char Pl8[16384];
    __shared__ __align__(16) unsigned char Xl8[16384];
    __shared__ float lpart[1024];
    int t = threadIdx.x;
    int wv = t >> 6, l = t & 63, lr = l & 15, lg = l >> 4;
    int w = blockIdx.x, b = blockIdx.y;
    f32x4 zero = {0.f,0.f,0.f,0.f};
    const unsigned char* qkb = qk8 + (size_t)b*NHW*64;
    // EARLY prefetch xcm8 half0 (independent of p1) -> overlaps QK^T+exp
    uint2 xg[4];
    #pragma unroll
    for (int it=0;it<4;it++){
        int fl = it*512 + t, c = fl >> 4, seg = fl & 15;
        xg[it] = *(const uint2*)(xcm8 + ((size_t)(b*NC + c)*NW + w)*NH + seg*8);
    }
    // ---- phase 1: swapped QK^T (fp8) + exp -> Pl8 packed fp8, partial sums ----
    i64 kf8 = u2ll(*(const uint2*)(qkb + ((size_t)((wv*16 + lr)*NW + w))*64 + 32 + lg*8));
    float psum[8];
    int j0 = wv*16 + lg*4;
    for (int ni=0; ni<8; ni++){
        i64 qf8 = u2ll(*(const uint2*)(qkb + ((size_t)((ni*16 + lr)*NW + w))*64 + lg*8));
        f32x4 e = __builtin_amdgcn_mfma_f32_16x16x32_fp8_fp8(kf8, qf8, zero, 0,0,0);
        int i = ni*16 + lr;
        float pv[4], ps = 0.f;
        #pragma unroll
        for (int r=0;r<4;r++){
            pv[r] = (j0 + r == i) ? 0.f : __expf(e[r]);   // diag mask
            ps += pv[r];
        }
        *(uint32*)&Pl8[i*128 + (j0 ^ ((i&15)<<3))] = pk_fp8x4(pv[0],pv[1],pv[2],pv[3]);
        ps += __shfl_xor(ps, 16);
        ps += __shfl_xor(ps, 32);      // sum over lg -> wave-strip sum for col i
        psum[ni] = ps;
    }
    if (l < 16){
        #pragma unroll
        for (int ni=0;ni<8;ni++) lpart[wv*128 + ni*16 + lr] = psum[ni];
    }
    __syncthreads();
    if (t < 128){
        float s = 0.f;
        #pragma unroll
        for (int v=0;v<8;v++) s += lpart[v*128 + t];
        lH[((size_t)(b*NH + t))*NW + w] = s;
    }
    for (int half=0; half<2; half++){
        // stage X half to Xl8 (raw fp8, swizzled)
        #pragma unroll
        for (int it=0;it<4;it++){
            int fl = it*512 + t, c = fl >> 4, seg = fl & 15;
            *(uint2*)&Xl8[c*128 + ((seg*8) ^ ((c&15)<<3))] = xg[it];
        }
        __syncthreads();
        if (half == 0){
            #pragma unroll
            for (int it=0;it<4;it++){
                int fl = it*512 + t, c = fl >> 4, seg = fl & 15;
                xg[it] = *(const uint2*)(xcm8 + ((size_t)(b*NC + 128 + c)*NW + w)*NH + seg*8);
            }
        }
        i64 xa8[4];
        #pragma unroll
        for (int kb=0;kb<4;kb++)
            xa8[kb] = u2ll(*(const uint2*)&Xl8[swz8(wv*16 + lr, kb*32 + lg*8)]);
        f32x4 acc8[8];
        __builtin_amdgcn_s_setprio(1);
        for (int nj=0;nj<8;nj++){
            acc8[nj] = zero;
            #pragma unroll
            for (int kb=0;kb<4;kb++){
                i64 pb8 = u2ll(*(const uint2*)&Pl8[swz8(nj*16 + lr, kb*32 + lg*8)]);
                acc8[nj] = __builtin_amdgcn_mfma_f32_16x16x32_fp8_fp8(xa8[kb], pb8, acc8[nj], 0,0,0);
            }
        }
        __builtin_amdgcn_s_setprio(0);
        __syncthreads();   // Xl8 frag reads done
        // retile accs into Xl8 as fp8 (D[c][i] -> [i][c-local])
        #pragma unroll
        for (int nj=0;nj<8;nj++){
            int i = nj*16 + lr, c4 = wv*16 + lg*4;
            *(uint32*)&Xl8[i*128 + (c4 ^ ((i&15)<<3))] =
                pk_fp8x4(acc8[nj][0], acc8[nj][1], acc8[nj][2], acc8[nj][3]);
        }
        __syncthreads();
        // coalesced agg8 write (8B/lane, full 128B half-rows)
        #pragma unroll
        for (int it=0;it<4;it++){
            int fl = it*512 + t, i = fl >> 4, seg = fl & 15;
            uint2 v = *(const uint2*)&Xl8[i*128 + ((seg*8) ^ ((i&15)<<3))];
            *(uint2*)(agg8 + ((size_t)(b*NHW + i*NW + w))*NC + half*128 + seg*8) = v;
        }
        if (half == 0) __syncthreads();   // writeback reads done before restage
    }
}

// ---------------- fused row attention + final conv (all-fp8 data path) ----------------
// NO min-waves launch bound (rounds 10/11: any VGPR cap below ~140 unified spills Facc).
__global__ __launch_bounds__(512) void k_rowfin(const unsigned char* __restrict__ qk8,
                                                const bf16* __restrict__ xbf,
                                                const unsigned char* __restrict__ agg8,
                                                const float* __restrict__ lH,
                                                const unsigned char* __restrict__ wvb8,
                                                const float* __restrict__ bv,
                                                const float* __restrict__ gamma,
                                                float* __restrict__ out){
    __shared__ __align__(16) unsigned char Pl8[16384];
    __shared__ __align__(16) unsigned char AggL8[16384];
    __shared__ __align__(16) float lpart[1024];   // rows 1..7 = wave partials; row 0 becomes linv
    int t = threadIdx.x;
    int wv = t >> 6, l = t & 63, lr = l & 15, lg = l >> 4;
    int h = blockIdx.x, b = blockIdx.y;
    f32x4 zero = {0.f,0.f,0.f,0.f};
    const size_t prow = (size_t)(b*NH + h)*NW;    // position base of row h
    float lhv = (t < 128) ? lH[prow + t] : 0.f;
    // EARLY independent prefetches -> overlap p1 compute
    uint2 ag[4];                                  // agg8 half0
    #pragma unroll
    for (int it=0;it<4;it++){
        int fl = it*512 + t, i = fl >> 4, seg = fl & 15;
        ag[it] = *(const uint2*)(agg8 + (prow + i)*NC + seg*8);
    }
    bf16x8 xraw[4];                               // xbf half0 A-frags (raw)
    {
        const bf16* xr0 = xbf + ((size_t)(b*NC + wv*16 + lr))*NHW + h*NW;
        #pragma unroll
        for (int kb=0;kb<4;kb++) xraw[kb] = *(const bf16x8*)(xr0 + kb*32 + lg*8);
    }
    // ---- p1: swapped QK^T (fp8) -> Pl8 packed fp8 ----
    i64 kf8 = u2ll(*(const uint2*)(qk8 + (prow + wv*16 + lr)*64 + 32 + lg*8));
    float psum[8];
    int j0 = wv*16 + lg*4;
    for (int ni=0; ni<8; ni++){
        i64 qf8 = u2ll(*(const uint2*)(qk8 + (prow + ni*16 + lr)*64 + lg*8));
        f32x4 e = __builtin_amdgcn_mfma_f32_16x16x32_fp8_fp8(kf8, qf8, zero, 0,0,0);
        int i = ni*16 + lr;
        float pv[4], ps = 0.f;
        #pragma unroll
        for (int r=0;r<4;r++){
            pv[r] = __expf(e[r]);            // no diag mask on row branch
            ps += pv[r];
        }
        *(uint32*)&Pl8[i*128 + (j0 ^ ((i&15)<<3))] = pk_fp8x4(pv[0],pv[1],pv[2],pv[3]);
        ps += __shfl_xor(ps, 16);
        ps += __shfl_xor(ps, 32);
        psum[ni] = ps;
    }
    // convert x frags to fp8 (VALU, after loads have landed)
    i64 xa8[4];
    #pragma unroll
    for (int kb=0;kb<4;kb++) xa8[kb] = bf8_to_fp8(xraw[kb]);
    if (l < 16){
        #pragma unroll
        for (int ni=0;ni<8;ni++) lpart[wv*128 + ni*16 + lr] = psum[ni];
    }
    __syncthreads();                 // Pl8, lpart visible
    if (t < 128){
        float s = 0.f;
        #pragma unroll
        for (int v=0;v<8;v++) s += lpart[v*128 + t];
        lpart[t] = 1.f/(lhv + s);    // linv lives in lpart[0..127]
    }
    // stage agg8 half0 into AggL8 (raw fp8, swizzled)
    #pragma unroll
    for (int it=0;it<4;it++){
        int fl = it*512 + t, i = fl >> 4, seg = fl & 15;
        *(uint2*)&AggL8[i*128 + ((seg*8) ^ ((i&15)<<3))] = ag[it];
    }
    __syncthreads();                 // AggL8 + linv visible
    f32x4 Facc[8][2] = {};
    for (int half=0; half<2; half++){
        // prefetch agg8 half1 during half0 compute
        if (half == 0){
            #pragma unroll
            for (int it=0;it<4;it++){
                int fl = it*512 + t, i = fl >> 4, seg = fl & 15;
                ag[it] = *(const uint2*)(agg8 + (prow + i)*NC + 128 + seg*8);
            }
        }
        // aggW (fp8 MFMA) + fp8 RMW combine
        __builtin_amdgcn_s_setprio(1);
        for (int nj=0;nj<8;nj++){
            f32x4 acc = zero;
            #pragma unroll
            for (int kb=0;kb<4;kb++){
                i64 pb8 = u2ll(*(const uint2*)&Pl8[swz8(nj*16 + lr, kb*32 + lg*8)]);
                acc = __builtin_amdgcn_mfma_f32_16x16x32_fp8_fp8(xa8[kb], pb8, acc, 0,0,0);
            }
            int i = nj*16 + lr, c4 = wv*16 + lg*4;
            uint32* ap = (uint32*)&AggL8[i*128 + (c4 ^ ((i&15)<<3))];
            uint32 oldv = *ap;
            f32x2 lo = __builtin_amdgcn_cvt_pk_f32_fp8((int)oldv, false);
            f32x2 hi = __builtin_amdgcn_cvt_pk_f32_fp8((int)oldv, true);
            *ap = pk_fp8x4(lo[0]+acc[0], lo[1]+acc[1], hi[0]+acc[2], hi[1]+acc[3]);
        }
        __builtin_amdgcn_s_setprio(0);
        __syncthreads();             // RMW done before Wv reads
        // prefetch xbf half1 A-frags (hidden under Wv GEMM)
        if (half == 0){
            const bf16* xr1 = xbf + ((size_t)(b*NC + 128 + wv*16 + lr))*NHW + h*NW;
            #pragma unroll
            for (int kb=0;kb<4;kb++) xraw[kb] = *(const bf16x8*)(xr1 + kb*32 + lg*8);
        }
        // partial Wv GEMM over this half (K=128, fp8 x fp8)
        __builtin_amdgcn_s_setprio(1);
        for (int kb2=0; kb2<4; kb2++){
            i64 bw8[2];
            #pragma unroll
            for (int nt=0;nt<2;nt++)
                bw8[nt] = u2ll(*(const uint2*)(wvb8 + (size_t)(wv*32 + nt*16 + lr)*NC + half*128 + kb2*32 + lg*8));
            #pragma unroll
            for (int pt=0;pt<8;pt++){
                i64 aa8 = u2ll(*(const uint2*)&AggL8[swz8(pt*16 + lr, kb2*32 + lg*8)]);
                Facc[pt][0] = __builtin_amdgcn_mfma_f32_16x16x32_fp8_fp8(aa8, bw8[0], Facc[pt][0], 0,0,0);
                Facc[pt][1] = __builtin_amdgcn_mfma_f32_16x16x32_fp8_fp8(aa8, bw8[1], Facc[pt][1], 0,0,0);
            }
        }
        __builtin_amdgcn_s_setprio(0);
        if (half == 0){
            __syncthreads();         // Wv reads done before restage
            #pragma unroll
            for (int it=0;it<4;it++){
                int fl = it*512 + t, i = fl >> 4, seg = fl & 15;
                *(uint2*)&AggL8[i*128 + ((seg*8) ^ ((i&15)<<3))] = ag[it];
            }
            #pragma unroll
            for (int kb=0;kb<4;kb++) xa8[kb] = bf8_to_fp8(xraw[kb]);
            __syncthreads();
        }
    }
    // epilogue: out = g*linv[p]*Facc + g*bv + xbf, float4 along p
    float g = gamma[0];
    #pragma unroll
    for (int nt=0;nt<2;nt++){
        int co = wv*32 + nt*16 + lr;
        float gb = g*bv[co];
        const bf16* xr   = xbf + ((size_t)(b*NC + co))*NHW + h*NW;
        float*      orow = out + ((size_t)(b*NC + co))*NHW + h*NW;
        #pragma unroll
        for (int pt=0;pt<8;pt++){
            int p4 = pt*16 + lg*4;
            float4 lv = *(const float4*)&lpart[p4];
            union { ushort4 u; bf16 hh[4]; } xv;
            xv.u = *(const ushort4*)(xr + p4);
            float4 ov;
            ov.x = g*lv.x*Facc[pt][nt][0] + gb + b2f(xv.hh[0]);
            ov.y = g*lv.y*Facc[pt][nt][1] + gb + b2f(xv.hh[1]);
            ov.z = g*lv.z*Facc[pt][nt][2] + gb + b2f(xv.hh[2]);
            ov.w = g*lv.w*Facc[pt][nt][3] + gb + b2f(xv.hh[3]);
            *(float4*)(orow + p4) = ov;
        }
    }
}

extern "C" void kernel_launch(void* const* d_in, const int* in_sizes, int n_in,
                              void* d_out, int out_size, void* d_ws, size_t ws_size,
                              hipStream_t stream){
    (void)in_sizes; (void)n_in; (void)out_size; (void)ws_size;
    const float* x     = (const float*)d_in[0];
    const float* Wq    = (const float*)d_in[1];
    const float* bq    = (const float*)d_in[2];
    const float* Wk    = (const float*)d_in[3];
    const float* bk    = (const float*)d_in[4];
    const float* Wv    = (const float*)d_in[5];
    const float* bv    = (const float*)d_in[6];
    const float* gamma = (const float*)d_in[7];
    float* out = (float*)d_out;
    char* ws = (char*)d_ws;

    unsigned char* qk8  = (unsigned char*) (ws + 0);          //  8,388,608  [b][p][64B] fp8 q|k
    unsigned char* xcm8 = (unsigned char*) (ws + 8388608);    // 33,554,432  [b][c][w][h] fp8
    bf16*          xbf  = (bf16*)          (ws + 41943040);   // 67,108,864  [b][c][h][w] bf16
    float*         lH   = (float*)         (ws + 109051904);  //    524,288  [b][i][w]
    unsigned char* wvb8 = (unsigned char*) (ws + 109576192);  //     65,536  [co][c] fp8
    bf16*          wqkb = (bf16*)          (ws + 109707264);  //     32,768  [64][256]
    unsigned char* agg8 = (unsigned char*) (ws + 109740032);  // 33,554,432  [b][p][c] fp8
    // total ws: 143,294,464 bytes

    k_prep  <<<dim3(192),     dim3(256), 0, stream>>>(Wq, Wk, Wv, wvb8, wqkb);
    k_tr    <<<dim3(4, 2048), dim3(256), 0, stream>>>(x, xcm8, xbf);
    k_qk    <<<dim3(64, 8),   dim3(512), 0, stream>>>(xbf, wqkb, bq, bk, qk8);
    k_colagg<<<dim3(128, 8),  dim3(512), 0, stream>>>(qk8, xcm8, agg8, lH);
    k_rowfin<<<dim3(128, 8),  dim3(512), 0, stream>>>(qk8, xbf, agg8, lH, wvb8, bv, gamma, out);
}

// Round 14
// 177.855 us; speedup vs baseline: 1.0767x; 1.0767x over previous
//
#include <hip/hip_runtime.h>
#include <hip/hip_bf16.h>

typedef __hip_bfloat16 bf16;
typedef __attribute__((ext_vector_type(8))) short bf16x8;
typedef __attribute__((ext_vector_type(4))) float f32x4;
typedef __attribute__((ext_vector_type(2))) float f32x2;
typedef unsigned int uint32;
typedef long long i64;

#define NB 8
#define NC 256
#define NH 128
#define NW 128
#define NHW 16384
#define QSTR 40    // k_qk Xl stride: 80B = 5*16B aligned

static __device__ __forceinline__ float b2f(bf16 v){ return __bfloat162float(v); }
static __device__ __forceinline__ bf16  f2b(float v){ return __float2bfloat16(v); }
// bf16 LDS tile swizzle (elem space, 16B granule): used by AggL
static __device__ __forceinline__ int swz(int row, int col){ return row*128 + (col ^ ((row&7)<<3)); }
// fp8 LDS tile swizzle (byte space, 8B granule)
static __device__ __forceinline__ int swz8(int row, int col){ return row*128 + (col ^ ((row&15)<<3)); }

// fp8 e4m3 (OCP) helpers
static __device__ __forceinline__ uint32 pk_fp8x4(float a, float b, float c, float d){
    int v = __builtin_amdgcn_cvt_pk_fp8_f32(a, b, 0, false);
    v = __builtin_amdgcn_cvt_pk_fp8_f32(c, d, v, true);
    return (uint32)v;
}
static __device__ __forceinline__ bf16x8 up_fp8x8(uint2 u){
    f32x2 a = __builtin_amdgcn_cvt_pk_f32_fp8((int)u.x, false);
    f32x2 b = __builtin_amdgcn_cvt_pk_f32_fp8((int)u.x, true);
    f32x2 c = __builtin_amdgcn_cvt_pk_f32_fp8((int)u.y, false);
    f32x2 d = __builtin_amdgcn_cvt_pk_f32_fp8((int)u.y, true);
    union { bf16x8 v; bf16 h[8]; } r;
    r.h[0]=f2b(a[0]); r.h[1]=f2b(a[1]); r.h[2]=f2b(b[0]); r.h[3]=f2b(b[1]);
    r.h[4]=f2b(c[0]); r.h[5]=f2b(c[1]); r.h[6]=f2b(d[0]); r.h[7]=f2b(d[1]);
    return r.v;
}
static __device__ __forceinline__ i64 u2ll(uint2 u){
    union { uint2 a; i64 b; } c; c.a = u; return c.b;
}
static __device__ __forceinline__ i64 bf8_to_fp8(bf16x8 v){
    union { bf16x8 v8; bf16 h[8]; } a; a.v8 = v;
    uint2 r;
    r.x = pk_fp8x4(b2f(a.h[0]), b2f(a.h[1]), b2f(a.h[2]), b2f(a.h[3]));
    r.y = pk_fp8x4(b2f(a.h[4]), b2f(a.h[5]), b2f(a.h[6]), b2f(a.h[7]));
    return u2ll(r);
}

// ---------------- prep: wvb[co][c] bf16, wqkb[o][c] bf16 (o<32: Wq row, o>=32: Wk row) --------
__global__ __launch_bounds__(256) void k_prep(const float* __restrict__ Wq,
                                              const float* __restrict__ Wk,
                                              const float* __restrict__ Wv,
                                              bf16* __restrict__ wvb,
                                              bf16* __restrict__ wqkb){
    int idx = blockIdx.x*256 + threadIdx.x;
    if (idx < 65536){
        wvb[idx] = f2b(Wv[idx]);                  // row-major [co][c]
    } else {
        int i2 = idx - 65536;                     // 0..16383 -> [64][256] flat
        wqkb[i2] = f2b(i2 < 8192 ? Wq[i2] : Wk[i2 - 8192]);
    }
}

// ---------------- 64x64 tiled transpose: x fp32 -> xbf bf16 [c][h][w] + xcm8 fp8 [c][w][h] ----
__global__ __launch_bounds__(256) void k_tr(const float* __restrict__ x,
                                            unsigned char* __restrict__ xcm8,
                                            bf16* __restrict__ xbf){
    __shared__ float tile[64][65];
    int img = blockIdx.y;                 // 0..2047 (b*c)
    int tw = blockIdx.x & 1, th = blockIdx.x >> 1;
    int h0 = th*64, w0 = tw*64;
    int t = threadIdx.x;
    const float* src = x + (size_t)img*NHW;
    #pragma unroll
    for (int it=0; it<4; it++){
        int fl = it*256 + t;
        int row = fl >> 4, c4 = (fl & 15) * 4;
        float4 v = *(const float4*)(src + (size_t)(h0+row)*NW + w0 + c4);
        tile[row][c4+0]=v.x; tile[row][c4+1]=v.y; tile[row][c4+2]=v.z; tile[row][c4+3]=v.w;
    }
    __syncthreads();
    bf16* db = xbf + (size_t)img*NHW;
    #pragma unroll
    for (int it=0; it<4; it++){
        int fl = it*256 + t;
        int row = fl >> 4, c4 = (fl & 15) * 4;
        union { ushort4 u; bf16 h[4]; } pk;
        #pragma unroll
        for (int k2=0;k2<4;k2++) pk.h[k2] = f2b(tile[row][c4+k2]);
        *(ushort4*)(db + (size_t)(h0+row)*NW + w0 + c4) = pk.u;
    }
    unsigned char* dc = xcm8 + (size_t)img*NHW;
    #pragma unroll
    for (int it=0; it<4; it++){
        int fl = it*256 + t;
        int wl = fl >> 4, hq = (fl & 15) * 4;
        uint32 u = pk_fp8x4(tile[hq+0][wl], tile[hq+1][wl], tile[hq+2][wl], tile[hq+3][wl]);
        *(uint32*)(dc + (size_t)(w0+wl)*NH + h0 + hq) = u;
    }
}

// ---------------- qk conv (MFMA): qk8[b][p][64] = {q fp8 0..31 | k fp8 32..63} ----------------
__global__ __launch_bounds__(512) void k_qk(const bf16* __restrict__ xbf,
                                            const bf16* __restrict__ wqkb,
                                            const float* __restrict__ bq,
                                            const float* __restrict__ bk,
                                            unsigned char* __restrict__ qk8){
    __shared__ __align__(16) bf16 Xl[256*QSTR];
    int t = threadIdx.x;
    int wv = t >> 6, l = t & 63, lr = l & 15, lg = l >> 4;
    int b = blockIdx.y;
    int p0 = blockIdx.x * 256;
    int q4 = t & 3, pb = ((t >> 2) & 63) * 4, chi = t >> 8;   // chi 0/1
    f32x4 acc[4][2] = {};
    for (int kb = 0; kb < 8; kb++){
        if (kb) __syncthreads();
        #pragma unroll
        for (int it = 0; it < 4; it++){
            int cl = it*8 + chi*4;                // chunk-local c base (lane adds q4)
            const bf16* xp = xbf + ((size_t)(b*NC + kb*32 + cl + q4))*NHW + p0 + pb;
            union { ushort4 u; bf16 h[4]; } ld;
            ld.u = *(const ushort4*)xp;
            float e[4] = {b2f(ld.h[0]), b2f(ld.h[1]), b2f(ld.h[2]), b2f(ld.h[3])};
            float s1[4], s2[4];
            #pragma unroll
            for (int j=0;j<4;j++){
                float ex = __shfl_xor(e[j^1], 1);
                s1[j] = ((j&1)==(q4&1)) ? e[j] : ex;
            }
            #pragma unroll
            for (int j=0;j<4;j++){
                float ex = __shfl_xor(s1[j^2], 2);
                s2[j] = ((j&2)==(q4&2)) ? s1[j] : ex;
            }
            union { ushort4 u; bf16 h[4]; } pk;
            #pragma unroll
            for (int j=0;j<4;j++) pk.h[j] = f2b(s2[j]);
            *(ushort4*)(Xl + (pb + q4)*QSTR + cl) = pk.u;
        }
        __syncthreads();
        bf16x8 bf_[2];
        #pragma unroll
        for (int nt=0;nt<2;nt++)
            bf_[nt] = *(const bf16x8*)(Xl + (wv*32 + nt*16 + lr)*QSTR + lg*8);
        #pragma unroll
        for (int mt=0;mt<4;mt++){
            bf16x8 af = *(const bf16x8*)(wqkb + (size_t)(mt*16 + lr)*NC + kb*32 + lg*8);
            acc[mt][0] = __builtin_amdgcn_mfma_f32_16x16x32_bf16(af, bf_[0], acc[mt][0], 0,0,0);
            acc[mt][1] = __builtin_amdgcn_mfma_f32_16x16x32_bf16(af, bf_[1], acc[mt][1], 0,0,0);
        }
    }
    #pragma unroll
    for (int mt=0;mt<4;mt++){
        int o0 = mt*16 + lg*4;                        // 0..63 (q rows 0..31, k rows 32..63)
        float4 bb = (mt < 2) ? *(const float4*)(bq + o0)
                             : *(const float4*)(bk + o0 - 32);
        #pragma unroll
        for (int nt=0;nt<2;nt++){
            int p = p0 + wv*32 + nt*16 + lr;
            uint32 v = pk_fp8x4(acc[mt][nt][0] + bb.x, acc[mt][nt][1] + bb.y,
                                acc[mt][nt][2] + bb.z, acc[mt][nt][3] + bb.w);
            *(uint32*)(qk8 + ((size_t)b*NHW + p)*64 + o0) = v;
        }
    }
}

// ---------------- column attention (fp8 MFMA): unnormalized aggH (fp8) + lH ----------------
__global__ __launch_bounds__(512, 6) void k_colagg(const unsigned char* __restrict__ qk8,
                                                   const unsigned char* __restrict__ xcm8,
                                                   unsigned char* __restrict__ agg8,
                                                   float* __restrict__ lH){
    __shared__ __align__(16) unsigned char Pl8[16384];
    __shared__ __align__(16) unsigned char Xl8[16384];
    __shared__ float lpart[1024];
    int t = threadIdx.x;
    int wv = t >> 6, l = t & 63, lr = l & 15, lg = l >> 4;
    int w = blockIdx.x, b = blockIdx.y;
    f32x4 zero = {0.f,0.f,0.f,0.f};
    const unsigned char* qkb = qk8 + (size_t)b*NHW*64;
    // ---- phase 1: swapped QK^T (fp8) + exp -> Pl8 packed fp8, partial sums ----
    i64 kf8 = u2ll(*(const uint2*)(qkb + ((size_t)((wv*16 + lr)*NW + w))*64 + 32 + lg*8));
    float psum[8];
    int j0 = wv*16 + lg*4;
    for (int ni=0; ni<8; ni++){
        i64 qf8 = u2ll(*(const uint2*)(qkb + ((size_t)((ni*16 + lr)*NW + w))*64 + lg*8));
        f32x4 e = __builtin_amdgcn_mfma_f32_16x16x32_fp8_fp8(kf8, qf8, zero, 0,0,0);
        int i = ni*16 + lr;
        float pv[4], ps = 0.f;
        #pragma unroll
        for (int r=0;r<4;r++){
            pv[r] = (j0 + r == i) ? 0.f : __expf(e[r]);   // diag mask
            ps += pv[r];
        }
        *(uint32*)&Pl8[i*128 + (j0 ^ ((i&15)<<3))] = pk_fp8x4(pv[0],pv[1],pv[2],pv[3]);
        ps += __shfl_xor(ps, 16);
        ps += __shfl_xor(ps, 32);      // sum over lg -> wave-strip sum for col i
        psum[ni] = ps;
    }
    // prefetch xcm8 half0 into regs (coalesced 8B/lane, full 128B rows)
    uint2 xg[4];
    #pragma unroll
    for (int it=0;it<4;it++){
        int fl = it*512 + t, c = fl >> 4, seg = fl & 15;
        xg[it] = *(const uint2*)(xcm8 + ((size_t)(b*NC + c)*NW + w)*NH + seg*8);
    }
    if (l < 16){
        #pragma unroll
        for (int ni=0;ni<8;ni++) lpart[wv*128 + ni*16 + lr] = psum[ni];
    }
    __syncthreads();
    if (t < 128){
        float s = 0.f;
        #pragma unroll
        for (int v=0;v<8;v++) s += lpart[v*128 + t];
        lH[((size_t)(b*NH + t))*NW + w] = s;
    }
    for (int half=0; half<2; half++){
        // stage X half to Xl8 (raw fp8, swizzled)
        #pragma unroll
        for (int it=0;it<4;it++){
            int fl = it*512 + t, c = fl >> 4, seg = fl & 15;
            *(uint2*)&Xl8[c*128 + ((seg*8) ^ ((c&15)<<3))] = xg[it];
        }
        __syncthreads();
        if (half == 0){
            #pragma unroll
            for (int it=0;it<4;it++){
                int fl = it*512 + t, c = fl >> 4, seg = fl & 15;
                xg[it] = *(const uint2*)(xcm8 + ((size_t)(b*NC + 128 + c)*NW + w)*NH + seg*8);
            }
        }
        i64 xa8[4];
        #pragma unroll
        for (int kb=0;kb<4;kb++)
            xa8[kb] = u2ll(*(const uint2*)&Xl8[swz8(wv*16 + lr, kb*32 + lg*8)]);
        f32x4 acc8[8];
        __builtin_amdgcn_s_setprio(1);
        for (int nj=0;nj<8;nj++){
            acc8[nj] = zero;
            #pragma unroll
            for (int kb=0;kb<4;kb++){
                i64 pb8 = u2ll(*(const uint2*)&Pl8[swz8(nj*16 + lr, kb*32 + lg*8)]);
                acc8[nj] = __builtin_amdgcn_mfma_f32_16x16x32_fp8_fp8(xa8[kb], pb8, acc8[nj], 0,0,0);
            }
        }
        __builtin_amdgcn_s_setprio(0);
        __syncthreads();   // Xl8 frag reads done
        // retile accs into Xl8 as fp8 (D[c][i] -> [i][c-local])
        #pragma unroll
        for (int nj=0;nj<8;nj++){
            int i = nj*16 + lr, c4 = wv*16 + lg*4;
            *(uint32*)&Xl8[i*128 + (c4 ^ ((i&15)<<3))] =
                pk_fp8x4(acc8[nj][0], acc8[nj][1], acc8[nj][2], acc8[nj][3]);
        }
        __syncthreads();
        // coalesced agg8 write (8B/lane, full 128B half-rows)
        #pragma unroll
        for (int it=0;it<4;it++){
            int fl = it*512 + t, i = fl >> 4, seg = fl & 15;
            uint2 v = *(const uint2*)&Xl8[i*128 + ((seg*8) ^ ((i&15)<<3))];
            *(uint2*)(agg8 + ((size_t)(b*NHW + i*NW + w))*NC + half*128 + seg*8) = v;
        }
        if (half == 0) __syncthreads();   // writeback reads done before restage
    }
}

// ---------------- fused row attention + final conv (fp8 P/QK, bf16 AggL/Wv) ----------------
// NO min-waves launch bound: unified VGPR demand is ~140 (64 acc + ~76 arch); any cap
// below that spills Facc/ag/xa8 to scratch (round 10: 600MB, round 11: 330MB of traffic).
__global__ __launch_bounds__(512) void k_rowfin(const unsigned char* __restrict__ qk8,
                                                const bf16* __restrict__ xbf,
                                                const unsigned char* __restrict__ agg8,
                                                const float* __restrict__ lH,
                                                const bf16* __restrict__ wvb,
                                                const float* __restrict__ bv,
                                                const float* __restrict__ gamma,
                                                float* __restrict__ out){
    __shared__ __align__(16) unsigned char Pl8[16384];
    __shared__ __align__(16) bf16 AggL[16384];
    __shared__ __align__(16) float lpart[1024];   // rows 1..7 = wave partials; row 0 becomes linv
    int t = threadIdx.x;
    int wv = t >> 6, l = t & 63, lr = l & 15, lg = l >> 4;
    int h = blockIdx.x, b = blockIdx.y;
    f32x4 zero = {0.f,0.f,0.f,0.f};
    const size_t prow = (size_t)(b*NH + h)*NW;    // position base of row h
    float lhv = (t < 128) ? lH[prow + t] : 0.f;
    // ---- p1: swapped QK^T (fp8) -> Pl8 packed fp8 ----
    i64 kf8 = u2ll(*(const uint2*)(qk8 + (prow + wv*16 + lr)*64 + 32 + lg*8));
    float psum[8];
    int j0 = wv*16 + lg*4;
    for (int ni=0; ni<8; ni++){
        i64 qf8 = u2ll(*(const uint2*)(qk8 + (prow + ni*16 + lr)*64 + lg*8));
        f32x4 e = __builtin_amdgcn_mfma_f32_16x16x32_fp8_fp8(kf8, qf8, zero, 0,0,0);
        int i = ni*16 + lr;
        float pv[4], ps = 0.f;
        #pragma unroll
        for (int r=0;r<4;r++){
            pv[r] = __expf(e[r]);            // no diag mask on row branch
            ps += pv[r];
        }
        *(uint32*)&Pl8[i*128 + (j0 ^ ((i&15)<<3))] = pk_fp8x4(pv[0],pv[1],pv[2],pv[3]);
        ps += __shfl_xor(ps, 16);
        ps += __shfl_xor(ps, 32);
        psum[ni] = ps;
    }
    // prefetch agg8 half0 (coalesced 8B/lane)
    uint2 ag[4];
    #pragma unroll
    for (int it=0;it<4;it++){
        int fl = it*512 + t, i = fl >> 4, seg = fl & 15;
        ag[it] = *(const uint2*)(agg8 + (prow + i)*NC + seg*8);
    }
    // prefetch xbf half0 A-frags and convert to fp8 in-reg
    i64 xa8[4];
    {
        const bf16* xr0 = xbf + ((size_t)(b*NC + wv*16 + lr))*NHW + h*NW;
        #pragma unroll
        for (int kb=0;kb<4;kb++) xa8[kb] = bf8_to_fp8(*(const bf16x8*)(xr0 + kb*32 + lg*8));
    }
    if (l < 16){
        #pragma unroll
        for (int ni=0;ni<8;ni++) lpart[wv*128 + ni*16 + lr] = psum[ni];
    }
    __syncthreads();                 // Pl8, lpart visible
    if (t < 128){
        float s = 0.f;
        #pragma unroll
        for (int v=0;v<8;v++) s += lpart[v*128 + t];
        lpart[t] = 1.f/(lhv + s);    // linv lives in lpart[0..127] (only col t touched by thread t)
    }
    // stage agg8 half0 into AggL (fp8 -> bf16, swizzled)
    #pragma unroll
    for (int it=0;it<4;it++){
        int fl = it*512 + t, i = fl >> 4, seg = fl & 15;
        *(bf16x8*)&AggL[i*128 + ((seg*8) ^ ((i&7)<<3))] = up_fp8x8(ag[it]);
    }
    __syncthreads();                 // AggL + linv visible
    f32x4 Facc[8][2] = {};
    for (int half=0; half<2; half++){
        // prefetch agg8 half1 during half0 compute
        if (half == 0){
            #pragma unroll
            for (int it=0;it<4;it++){
                int fl = it*512 + t, i = fl >> 4, seg = fl & 15;
                ag[it] = *(const uint2*)(agg8 + (prow + i)*NC + 128 + seg*8);
            }
        }
        // aggW (fp8 MFMA) + plain-add combine (LDS RMW)
        __builtin_amdgcn_s_setprio(1);
        for (int nj=0;nj<8;nj++){
            f32x4 acc = zero;
            #pragma unroll
            for (int kb=0;kb<4;kb++){
                i64 pb8 = u2ll(*(const uint2*)&Pl8[swz8(nj*16 + lr, kb*32 + lg*8)]);
                acc = __builtin_amdgcn_mfma_f32_16x16x32_fp8_fp8(xa8[kb], pb8, acc, 0,0,0);
            }
            int i = nj*16 + lr, c4 = wv*16 + lg*4;
            bf16* ap = &AggL[i*128 + (c4 ^ ((i&7)<<3))];
            union { ushort4 u; bf16 hh[4]; } old, nu;
            old.u = *(const ushort4*)ap;
            #pragma unroll
            for (int r=0;r<4;r++) nu.hh[r] = f2b(b2f(old.hh[r]) + acc[r]);
            *(ushort4*)ap = nu.u;
        }
        __builtin_amdgcn_s_setprio(0);
        __syncthreads();             // RMW done before Wv reads
        // prefetch+convert xbf half1 A-frags (hidden under Wv GEMM)
        i64 xb2[4];
        if (half == 0){
            const bf16* xr1 = xbf + ((size_t)(b*NC + 128 + wv*16 + lr))*NHW + h*NW;
            #pragma unroll
            for (int kb=0;kb<4;kb++) xb2[kb] = bf8_to_fp8(*(const bf16x8*)(xr1 + kb*32 + lg*8));
        }
        // partial Wv GEMM over this half (K=128, bf16)
        __builtin_amdgcn_s_setprio(1);
        for (int kb2=0; kb2<4; kb2++){
            bf16x8 bw[2];
            #pragma unroll
            for (int nt=0;nt<2;nt++)
                bw[nt] = *(const bf16x8*)(wvb + (size_t)(wv*32 + nt*16 + lr)*NC + half*128 + kb2*32 + lg*8);
            #pragma unroll
            for (int pt=0;pt<8;pt++){
                bf16x8 aa = *(const bf16x8*)&AggL[swz(pt*16 + lr, kb2*32 + lg*8)];
                Facc[pt][0] = __builtin_amdgcn_mfma_f32_16x16x32_bf16(aa, bw[0], Facc[pt][0], 0,0,0);
                Facc[pt][1] = __builtin_amdgcn_mfma_f32_16x16x32_bf16(aa, bw[1], Facc[pt][1], 0,0,0);
            }
        }
        __builtin_amdgcn_s_setprio(0);
        if (half == 0){
            __syncthreads();         // Wv reads done before restage
            #pragma unroll
            for (int it=0;it<4;it++){
                int fl = it*512 + t, i = fl >> 4, seg = fl & 15;
                *(bf16x8*)&AggL[i*128 + ((seg*8) ^ ((i&7)<<3))] = up_fp8x8(ag[it]);
            }
            #pragma unroll
            for (int kb=0;kb<4;kb++) xa8[kb] = xb2[kb];
            __syncthreads();
        }
    }
    // epilogue: out = g*linv[p]*Facc + g*bv + xbf, float4 along p
    float g = gamma[0];
    #pragma unroll
    for (int nt=0;nt<2;nt++){
        int co = wv*32 + nt*16 + lr;
        float gb = g*bv[co];
        const bf16* xr   = xbf + ((size_t)(b*NC + co))*NHW + h*NW;
        float*      orow = out + ((size_t)(b*NC + co))*NHW + h*NW;
        #pragma unroll
        for (int pt=0;pt<8;pt++){
            int p4 = pt*16 + lg*4;
            float4 lv = *(const float4*)&lpart[p4];
            union { ushort4 u; bf16 hh[4]; } xv;
            xv.u = *(const ushort4*)(xr + p4);
            float4 ov;
            ov.x = g*lv.x*Facc[pt][nt][0] + gb + b2f(xv.hh[0]);
            ov.y = g*lv.y*Facc[pt][nt][1] + gb + b2f(xv.hh[1]);
            ov.z = g*lv.z*Facc[pt][nt][2] + gb + b2f(xv.hh[2]);
            ov.w = g*lv.w*Facc[pt][nt][3] + gb + b2f(xv.hh[3]);
            *(float4*)(orow + p4) = ov;
        }
    }
}

extern "C" void kernel_launch(void* const* d_in, const int* in_sizes, int n_in,
                              void* d_out, int out_size, void* d_ws, size_t ws_size,
                              hipStream_t stream){
    (void)in_sizes; (void)n_in; (void)out_size; (void)ws_size;
    const float* x     = (const float*)d_in[0];
    const float* Wq    = (const float*)d_in[1];
    const float* bq    = (const float*)d_in[2];
    const float* Wk    = (const float*)d_in[3];
    const float* bk    = (const float*)d_in[4];
    const float* Wv    = (const float*)d_in[5];
    const float* bv    = (const float*)d_in[6];
    const float* gamma = (const float*)d_in[7];
    float* out = (float*)d_out;
    char* ws = (char*)d_ws;

    unsigned char* qk8  = (unsigned char*) (ws + 0);          //  8,388,608  [b][p][64B] fp8 q|k
    unsigned char* xcm8 = (unsigned char*) (ws + 8388608);    // 33,554,432  [b][c][w][h] fp8
    bf16*          xbf  = (bf16*)          (ws + 41943040);   // 67,108,864  [b][c][h][w] bf16
    float*         lH   = (float*)         (ws + 109051904);  //    524,288  [b][i][w]
    bf16*          wvb  = (bf16*)          (ws + 109576192);  //    131,072  [co][c]
    bf16*          wqkb = (bf16*)          (ws + 109707264);  //     32,768  [64][256]
    unsigned char* agg8 = (unsigned char*) (ws + 109740032);  // 33,554,432  [b][p][c] fp8
    // total ws: 143,294,464 bytes

    k_prep  <<<dim3(320),     dim3(256), 0, stream>>>(Wq, Wk, Wv, wvb, wqkb);
    k_tr    <<<dim3(4, 2048), dim3(256), 0, stream>>>(x, xcm8, xbf);
    k_qk    <<<dim3(64, 8),   dim3(512), 0, stream>>>(xbf, wqkb, bq, bk, qk8);
    k_colagg<<<dim3(128, 8),  dim3(512), 0, stream>>>(qk8, xcm8, agg8, lH);
    k_rowfin<<<dim3(128, 8),  dim3(512), 0, stream>>>(qk8, xbf, agg8, lH, wvb, bv, gamma, out);
}